// Round 13
// baseline (420.694 us; speedup 1.0000x reference)
//
#include <hip/hip_runtime.h>
#include <hip/hip_bf16.h>

typedef __bf16 bf16;
typedef __bf16 bf16x4 __attribute__((ext_vector_type(4)));
typedef __bf16 bf16x8 __attribute__((ext_vector_type(8)));
typedef float f32x4 __attribute__((ext_vector_type(4)));
typedef unsigned short ushort8_t __attribute__((ext_vector_type(8)));
typedef unsigned int u32x2 __attribute__((ext_vector_type(2)));

#define GLOAD_LDS16(g, l)                                                      \
    __builtin_amdgcn_global_load_lds(                                          \
        (const __attribute__((address_space(1))) void*)(g),                    \
        (__attribute__((address_space(3))) void*)(l), 16, 0, 0)

// pinned raw barrier: sched_barrier(0) fences IR motion across it (rule #18/m152)
#define SBAR()                                                                 \
    do {                                                                       \
        __builtin_amdgcn_sched_barrier(0);                                     \
        __builtin_amdgcn_s_barrier();                                          \
        __builtin_amdgcn_sched_barrier(0);                                     \
    } while (0)

// Problem constants
// B=4, S=4096, H=1024, G=256, W=8, CHUNK=1024, NUM_HEADS=4, hd=256
// M = B*S = 16384 rows, NC = 16 chunks

// ---------------- wavelet kernel normalization ----------------
__global__ __launch_bounds__(256) void k_wavelet(const float* __restrict__ mw,
                                                 const float* __restrict__ sc,
                                                 float* __restrict__ kern) {
    int w = blockIdx.x;
    int tid = threadIdx.x;
    float s = 0.f;
    for (int h = tid; h < 1024; h += 256) { float v = mw[w * 1024 + h]; s += v * v; }
#pragma unroll
    for (int xm = 1; xm < 64; xm <<= 1) s += __shfl_xor(s, xm);
    __shared__ float red[4];
    if ((tid & 63) == 0) red[tid >> 6] = s;
    __syncthreads();
    float tot = red[0] + red[1] + red[2] + red[3];
    float inv = 1.f / fmaxf(sqrtf(tot), 1e-12f);
    float sg = 1.f / (1.f + __expf(-sc[w]));
    float m = inv * sg;
    for (int h = tid; h < 1024; h += 256) kern[w * 1024 + h] = mw[w * 1024 + h] * m;
}

// ---------------- coeffs = xc @ kern^T  (16384 x 8) ----------------
__global__ __launch_bounds__(256) void k_coeffs(const float* __restrict__ x,
                                                const float* __restrict__ kern,
                                                float* __restrict__ coeffs) {
    __shared__ float kl[8 * 1024];
    int tid = threadIdx.x;
    for (int i = tid; i < 8192; i += 256) kl[i] = kern[i];
    __syncthreads();
    int wid = tid >> 6, lane = tid & 63;
    long row = (long)blockIdx.x * 4 + wid;
    float acc[8] = {0, 0, 0, 0, 0, 0, 0, 0};
    const float* xr = x + row * 1024;
    for (int i = 0; i < 16; i++) {
        float xv = xr[lane + i * 64];
#pragma unroll
        for (int w = 0; w < 8; w++) acc[w] += xv * kl[w * 1024 + lane + i * 64];
    }
#pragma unroll
    for (int xm = 1; xm < 64; xm <<= 1) {
#pragma unroll
        for (int w = 0; w < 8; w++) acc[w] += __shfl_xor(acc[w], xm);
    }
    if (lane == 0) {
#pragma unroll
        for (int w = 0; w < 8; w++) coeffs[row * 8 + w] = acc[w];
    }
}

// ---------------- hid = LN(coeffs@w1 + b1); g = gelu(hid) (bf16) ----------------
__global__ __launch_bounds__(256) void k_mix1(const float* __restrict__ coeffs,
                                              const float* __restrict__ w1,
                                              const float* __restrict__ b1,
                                              const float* __restrict__ lng,
                                              const float* __restrict__ lnb,
                                              bf16* __restrict__ g) {
    long row = blockIdx.x;
    int tid = threadIdx.x;
    int wid = tid >> 6, lane = tid & 63;
    __shared__ float cf[8];
    __shared__ float red1[4], red2[4];
    if (tid < 8) cf[tid] = coeffs[row * 8 + tid];
    __syncthreads();
    float h0[2];
#pragma unroll
    for (int t = 0; t < 2; t++) {
        int j = tid + t * 256;
        float a = b1[j];
#pragma unroll
        for (int w = 0; w < 8; w++) a += cf[w] * w1[w * 512 + j];
        h0[t] = a;
    }
    float s1 = h0[0] + h0[1];
    float s2 = h0[0] * h0[0] + h0[1] * h0[1];
#pragma unroll
    for (int xm = 1; xm < 64; xm <<= 1) {
        s1 += __shfl_xor(s1, xm);
        s2 += __shfl_xor(s2, xm);
    }
    if (lane == 0) { red1[wid] = s1; red2[wid] = s2; }
    __syncthreads();
    s1 = red1[0] + red1[1] + red1[2] + red1[3];
    s2 = red2[0] + red2[1] + red2[2] + red2[3];
    float mean = s1 * (1.f / 512.f);
    float var = s2 * (1.f / 512.f) - mean * mean;
    float inv = rsqrtf(var + 1e-5f);
#pragma unroll
    for (int t = 0; t < 2; t++) {
        int j = tid + t * 256;
        float xn = (h0[t] - mean) * inv * lng[j] + lnb[j];
        float ge = 0.5f * xn * (1.f + erff(xn * 0.70710678118654752f));
        g[row * 512 + j] = (bf16)ge;
    }
}

// ---------------- fused weight transpose + bf16 convert (all 6 weights, 1 launch) ----------------
__global__ void k_wtrans_all(const float* __restrict__ w2, const float* __restrict__ wq,
                             const float* __restrict__ wk, const float* __restrict__ wv,
                             const float* __restrict__ wo, const float* __restrict__ ow,
                             bf16* __restrict__ w2t, bf16* __restrict__ wqt,
                             bf16* __restrict__ wkt, bf16* __restrict__ wvt,
                             bf16* __restrict__ wot, bf16* __restrict__ owt) {
    long idx = (long)blockIdx.x * 256 + threadIdx.x;
    if (idx < 524288) {                       // w2: K=512, N=1024
        int kk = (int)(idx >> 10), n = (int)(idx & 1023);
        w2t[(long)n * 512 + kk] = (bf16)w2[idx];
    } else if (idx < 4718592) {               // wq,wk,wv,wo: K=N=1024
        long r = idx - 524288;
        int m = (int)(r >> 20);
        long q = r & 1048575;
        int kk = (int)(q >> 10), n = (int)(q & 1023);
        const float* src = (m == 0) ? wq : (m == 1) ? wk : (m == 2) ? wv : wo;
        bf16* dst = (m == 0) ? wqt : (m == 1) ? wkt : (m == 2) ? wvt : wot;
        dst[(long)n * 1024 + kk] = (bf16)src[q];
    } else {                                  // ow: K=1024, N=256
        long r = idx - 4718592;
        int kk = (int)(r >> 8), n = (int)(r & 255);
        owt[(long)n * 1024 + kk] = (bf16)ow[r];
    }
}

enum { EPI_BF16 = 0, EPI_BF16_BIAS = 1, EPI_F32_BIAS = 2, EPI_VT = 3, EPI_F32 = 4 };

// ---------------- GEMM 256x256, 8 waves, BK=64, 8-PHASE schedule (T1+T2+T3+T4+T5) ----------------
// verified R10/R12: 460->431->414 us path
template <int EPI>
__global__ __launch_bounds__(512, 2) void k_gemm8p(const bf16* __restrict__ A,
                                                   const bf16* __restrict__ Bt,
                                                   const float* __restrict__ bias,
                                                   void* __restrict__ Cout,
                                                   int K, int lda, int ldb, int ldc,
                                                   float scale) {
    __shared__ bf16 As[2 * 2 * 128 * 64];   // [buf][half][128][64] = 64 KB
    __shared__ bf16 Bs[2 * 2 * 128 * 64];   // 64 KB
    const int tid = threadIdx.x;
    const int wid = tid >> 6, lane = tid & 63;
    const int wr = wid >> 2, wc = wid & 3;   // 2x4 wave grid; wave owns 128x64
    // T1: bijective XCD chunk remap (grid = 4 x 64 = 256 blocks, 256 % 8 == 0)
    const int L = blockIdx.y * 4 + blockIdx.x;
    const int logical = ((L & 7) << 5) + (L >> 3);
    const long m0 = (long)(logical >> 2) * 256, n0 = (long)(logical & 3) * 256;
    f32x4 acc[8][4] = {};
    const int lr = lane & 15, gq = lane >> 4;
    const int l7 = lr & 7;

    const int srow = wid * 8 + (lane >> 3);
    const int sg = (lane & 7) ^ (lane >> 3);
    const bf16* aS = A + (m0 + srow) * lda + sg * 8;
    const bf16* bS = Bt + (n0 + srow) * ldb + sg * 8;

    auto stageA = [&](int t, int h) {
        bf16* d = As + (((t & 1) * 2 + h) * 128) * 64 + wid * 512;
        const long kq = (long)t << 6;
        GLOAD_LDS16(aS + (long)(h * 128) * lda + kq, d);
        GLOAD_LDS16(aS + (long)(h * 128 + 64) * lda + kq, d + 4096);
    };
    auto stageB = [&](int t, int h) {
        bf16* d = Bs + (((t & 1) * 2 + h) * 128) * 64 + wid * 512;
        const long kq = (long)t << 6;
        GLOAD_LDS16(bS + (long)(h * 128) * ldb + kq, d);
        GLOAD_LDS16(bS + (long)(h * 128 + 64) * ldb + kq, d + 4096);
    };

    bf16x8 bfr[4][2];
    auto ldB = [&](int b) {
#pragma unroll
        for (int j = 0; j < 4; j++)
#pragma unroll
            for (int kk = 0; kk < 2; kk++)
                bfr[j][kk] = *(const bf16x8*)&Bs[((b * 2 + (wc >> 1)) * 128 +
                                                 (wc & 1) * 64 + j * 16 + lr) * 64 +
                                                (((kk * 4 + gq) ^ l7) << 3)];
    };

    const int nt = K >> 6;        // K-tiles
    const int niter = nt >> 1;

    // prologue: tile0 (A,B) + B(1); vmcnt(4) leaves B(1) in flight
    stageA(0, 0); stageA(0, 1); stageB(0, 0); stageB(0, 1);
    stageB(1, 0); stageB(1, 1);
    asm volatile("s_waitcnt vmcnt(4)" ::: "memory");
    SBAR();

    for (int jit = 0; jit < niter - 1; ++jit) {
        const int T = jit << 1;
#pragma unroll
        for (int tp = 0; tp < 2; ++tp) {
#pragma unroll
            for (int q = 0; q < 4; ++q) {
                bf16x8 af[2][2];
                if (q == 0) ldB(tp);
#pragma unroll
                for (int ii = 0; ii < 2; ii++)
#pragma unroll
                    for (int kk = 0; kk < 2; kk++)
                        af[ii][kk] = *(const bf16x8*)&As[((tp * 2 + wr) * 128 +
                                                         (q * 2 + ii) * 16 + lr) * 64 +
                                                        (((kk * 4 + gq) ^ l7) << 3)];
                if (tp == 0) {
                    if (q == 0) stageA(T + 1, 0);
                    else if (q == 1) stageA(T + 1, 1);
                    else if (q == 2) stageB(T + 2, 0);
                    else stageB(T + 2, 1);
                } else {
                    if (q == 0) stageA(T + 2, 0);
                    else if (q == 1) stageA(T + 2, 1);
                    else if (q == 2) stageB(T + 3, 0);
                    else stageB(T + 3, 1);
                }
                if (q == 3) asm volatile("s_waitcnt vmcnt(4)" ::: "memory");
                SBAR();
                asm volatile("s_waitcnt lgkmcnt(0)" ::: "memory");
                __builtin_amdgcn_s_setprio(1);
#pragma unroll
                for (int ii = 0; ii < 2; ii++)
#pragma unroll
                    for (int j = 0; j < 4; j++) {
                        acc[q * 2 + ii][j] = __builtin_amdgcn_mfma_f32_16x16x32_bf16(
                            af[ii][0], bfr[j][0], acc[q * 2 + ii][j], 0, 0, 0);
                        acc[q * 2 + ii][j] = __builtin_amdgcn_mfma_f32_16x16x32_bf16(
                            af[ii][1], bfr[j][1], acc[q * 2 + ii][j], 0, 0, 0);
                    }
                __builtin_amdgcn_s_setprio(0);
                SBAR();
            }
        }
    }
    // final iteration (T = nt-2): stage only A(T+1); vmcnt(0) at phase 4
    {
        const int T = nt - 2;
#pragma unroll
        for (int tp = 0; tp < 2; ++tp) {
#pragma unroll
            for (int q = 0; q < 4; ++q) {
                bf16x8 af[2][2];
                if (q == 0) ldB(tp);
#pragma unroll
                for (int ii = 0; ii < 2; ii++)
#pragma unroll
                    for (int kk = 0; kk < 2; kk++)
                        af[ii][kk] = *(const bf16x8*)&As[((tp * 2 + wr) * 128 +
                                                         (q * 2 + ii) * 16 + lr) * 64 +
                                                        (((kk * 4 + gq) ^ l7) << 3)];
                if (tp == 0 && q == 0) stageA(T + 1, 0);
                if (tp == 0 && q == 1) stageA(T + 1, 1);
                if (tp == 0 && q == 3) asm volatile("s_waitcnt vmcnt(0)" ::: "memory");
                SBAR();
                asm volatile("s_waitcnt lgkmcnt(0)" ::: "memory");
                __builtin_amdgcn_s_setprio(1);
#pragma unroll
                for (int ii = 0; ii < 2; ii++)
#pragma unroll
                    for (int j = 0; j < 4; j++) {
                        acc[q * 2 + ii][j] = __builtin_amdgcn_mfma_f32_16x16x32_bf16(
                            af[ii][0], bfr[j][0], acc[q * 2 + ii][j], 0, 0, 0);
                        acc[q * 2 + ii][j] = __builtin_amdgcn_mfma_f32_16x16x32_bf16(
                            af[ii][1], bfr[j][1], acc[q * 2 + ii][j], 0, 0, 0);
                    }
                __builtin_amdgcn_s_setprio(0);
                SBAR();
            }
        }
    }

    const int r0 = (lane >> 4) << 2;
#pragma unroll
    for (int i = 0; i < 8; i++) {
#pragma unroll
        for (int j = 0; j < 4; j++) {
#pragma unroll
            for (int e = 0; e < 4; e++) {
                long m = m0 + wr * 128 + i * 16 + r0 + e;
                long n = n0 + wc * 64 + j * 16 + lr;
                float v = acc[i][j][e] * scale;
                if constexpr (EPI == EPI_BF16_BIAS || EPI == EPI_F32_BIAS) v += bias[n];
                if constexpr (EPI == EPI_F32_BIAS || EPI == EPI_F32) {
                    ((float*)Cout)[m * ldc + n] = v;
                } else if constexpr (EPI == EPI_VT) {
                    long c = m >> 10, s = m & 1023, h = n >> 8, d = n & 255;
                    ((bf16*)Cout)[(((c << 2) + h) << 18) + (d << 10) + s] = (bf16)v;
                } else {
                    ((bf16*)Cout)[m * ldc + n] = (bf16)v;
                }
            }
        }
    }
}

// ---------------- GEMM 128x128 (m97 structure) — for the N=256 final GEMM ----------------
template <int EPI>
__global__ __launch_bounds__(256) void k_gemm(const bf16* __restrict__ A,
                                              const bf16* __restrict__ Bt,
                                              const float* __restrict__ bias,
                                              void* __restrict__ Cout,
                                              int M, int N, int K,
                                              int lda, int ldb, int ldc, float scale) {
    __shared__ bf16 As[128 * 32];
    __shared__ bf16 Bs[128 * 32];
    int tid = threadIdx.x;
    int wid = tid >> 6, lane = tid & 63;
    int wr = wid >> 1, wc = wid & 1;
    // T1 XCD remap (grid 2 x 128 = 256 blocks)
    const int L = blockIdx.y * 2 + blockIdx.x;
    const int logical = ((L & 7) << 5) + (L >> 3);
    long m0 = (long)(logical >> 1) * 128, n0 = (long)(logical & 1) * 128;
    f32x4 acc[4][4] = {};
    const int lr = lane & 15, ko = (lane >> 4) << 3;

    const int srow = wid * 32 + (lane >> 2);
    const int scol = (lane & 3) << 3;
    const bf16* a0 = A + (m0 + srow) * lda + scol;
    const bf16* a1 = A + (m0 + srow + 16) * lda + scol;
    const bf16* b0 = Bt + (n0 + srow) * ldb + scol;
    const bf16* b1 = Bt + (n0 + srow + 16) * ldb + scol;
    bf16* la0 = As + wid * 1024;
    bf16* la1 = As + wid * 1024 + 512;
    bf16* lb0 = Bs + wid * 1024;
    bf16* lb1 = Bs + wid * 1024 + 512;

    for (int k0 = 0; k0 < K; k0 += 32) {
        GLOAD_LDS16(a0 + k0, la0);
        GLOAD_LDS16(a1 + k0, la1);
        GLOAD_LDS16(b0 + k0, lb0);
        GLOAD_LDS16(b1 + k0, lb1);
        __syncthreads();
        bf16x8 af[4], bfr[4];
#pragma unroll
        for (int i = 0; i < 4; i++)
            af[i] = *(const bf16x8*)&As[(wr * 64 + i * 16 + lr) * 32 + ko];
#pragma unroll
        for (int i = 0; i < 4; i++)
            bfr[i] = *(const bf16x8*)&Bs[(wc * 64 + i * 16 + lr) * 32 + ko];
#pragma unroll
        for (int i = 0; i < 4; i++) {
#pragma unroll
            for (int j = 0; j < 4; j++)
                acc[i][j] = __builtin_amdgcn_mfma_f32_16x16x32_bf16(af[i], bfr[j], acc[i][j], 0, 0, 0);
        }
        __syncthreads();
    }
    const int r0 = (lane >> 4) << 2;
#pragma unroll
    for (int i = 0; i < 4; i++) {
#pragma unroll
        for (int j = 0; j < 4; j++) {
#pragma unroll
            for (int e = 0; e < 4; e++) {
                long m = m0 + wr * 64 + i * 16 + r0 + e;
                long n = n0 + wc * 64 + j * 16 + lr;
                float v = acc[i][j][e] * scale;
                if constexpr (EPI == EPI_BF16_BIAS || EPI == EPI_F32_BIAS) v += bias[n];
                if constexpr (EPI == EPI_F32_BIAS || EPI == EPI_F32) {
                    ((float*)Cout)[m * ldc + n] = v;
                } else {
                    ((bf16*)Cout)[m * ldc + n] = (bf16)v;
                }
            }
        }
    }
}

// ---------------- flash attention: 8 waves, 128 q-rows/block, KVBLK=64, SWAPPED QK^T ----------------
// mfma(K,Q) -> S^T: lane holds q = lane&15 (one q-col), kv = 16n + 4*(lane>>4) + reg.
// Softmax fully per-lane (2 shfl for cross-group reduce). P^T converts in-register to
// the PV A-fragment via the contraction permutation sigma(8g+e) = {16*n0+4g+e, 16*n1+4g+e-4};
// V B-fragment = two b64 reads at matching (swizzled) columns. No P LDS round-trip,
// no lgkmcnt(0) drains, no tr_reads. oacc rescale / final divide re-fetch per-q state
// via 4 shfl (rescale is defer-max rare; divide once).
__global__ __launch_bounds__(512, 2) void k_attn(const bf16* __restrict__ q,
                                                 const bf16* __restrict__ k,
                                                 const bf16* __restrict__ vt,
                                                 bf16* __restrict__ ao) {
    __shared__ __align__(16) bf16 smem[2 * 16384 + 2 * 16384];
    bf16* Ks = smem;            // [2][64 kv][256 d]
    bf16* Vs = smem + 32768;    // [2][256 d][64 kv]
    int tid = threadIdx.x;
    int wid = tid >> 6, lane = tid & 63;
    int c = blockIdx.x, h = blockIdx.y, q0 = blockIdx.z * 128;
    const int lr = lane & 15, gq = lane >> 4, ko = gq << 3;
    const int l7 = lr & 7;

    const int krw = wid * 2 + (lane >> 5);                 // 0..15
    const int kg = (lane & 31) ^ (krw & 7);
    const bf16* ksrc = k + ((long)c << 10) * 1024 + h * 256 + kg * 8;
    const int vrw = wid * 8 + ((lane >> 3) & 7);           // 0..63
    const int vg = (lane & 7) ^ ((lane >> 3) & 7);
    const bf16* vsrc = vt + ((long)(c * 4 + h) << 18) + vg * 8;

    long qrow = ((long)c << 10) + q0 + wid * 16 + lr;
    bf16x8 qf[8];
#pragma unroll
    for (int kk = 0; kk < 8; kk++)
        qf[kk] = *(const bf16x8*)&q[qrow * 1024 + h * 256 + kk * 32 + ko];

    f32x4 oacc[16] = {};
    float m_run = -1e30f, l_run = 0.f;     // per-lane softmax state for q = lr

    // V read column offsets (elements), X in {0,1}: global granules 4X+(gq>>1) and
    // 4X+2+(gq>>1), swizzled ^l7; +4-elem half-granule offset for odd gq.
    const int vco[4] = {
        (((gq >> 1) ^ l7) << 3) + ((gq & 1) << 2),
        (((2 + (gq >> 1)) ^ l7) << 3) + ((gq & 1) << 2),
        (((4 + (gq >> 1)) ^ l7) << 3) + ((gq & 1) << 2),
        (((6 + (gq >> 1)) ^ l7) << 3) + ((gq & 1) << 2)};

    // prologue: stage kb=0 into buf 0
#pragma unroll
    for (int i = 0; i < 4; i++) {
        GLOAD_LDS16(ksrc + (long)(i * 16 + krw) * 1024, Ks + i * 4096 + wid * 512);
        GLOAD_LDS16(vsrc + (long)(i * 64 + vrw) * 1024, Vs + i * 4096 + wid * 512);
    }
    __syncthreads();
    int buf = 0;
    for (int t = 0; t < 16; t++) {
        if (t < 15) {
            const int kb = (t + 1) << 6;
            const int ob = (buf ^ 1) << 14;
#pragma unroll
            for (int i = 0; i < 4; i++) {
                GLOAD_LDS16(ksrc + (long)(kb + i * 16 + krw) * 1024, Ks + ob + i * 4096 + wid * 512);
                GLOAD_LDS16(vsrc + (long)(i * 64 + vrw) * 1024 + kb, Vs + ob + i * 4096 + wid * 512);
            }
        }
        const bf16* Kc = Ks + (buf << 14);
        const bf16* Vc = Vs + (buf << 14);
        // QK^T swapped: st[n] = S^T tile n (kv rows 16n.., q cols)
        f32x4 st[4] = {};
        __builtin_amdgcn_s_setprio(1);
#pragma unroll
        for (int kk = 0; kk < 8; kk++) {
#pragma unroll
            for (int n = 0; n < 4; n++)
                st[n] = __builtin_amdgcn_mfma_f32_16x16x32_bf16(
                    *(const bf16x8*)&Kc[((n * 16 + lr) << 8) + ((((kk << 2) + gq) ^ l7) << 3)],
                    qf[kk], st[n], 0, 0, 0);
        }
        __builtin_amdgcn_s_setprio(0);
        // per-lane softmax over 16 regs (q = lr)
        float mx = st[0][0];
#pragma unroll
        for (int n = 0; n < 4; n++)
#pragma unroll
            for (int e = 0; e < 4; e++) mx = fmaxf(mx, st[n][e]);
        mx = fmaxf(mx, __shfl_xor(mx, 16));
        mx = fmaxf(mx, __shfl_xor(mx, 32));
        // defer-max (T13, THR=8)
        if (__any(mx > m_run + 8.f)) {
            float mn = fmaxf(m_run, mx);
            float al = __expf(m_run - mn);
            m_run = mn;
            l_run *= al;
            float alx[4];
#pragma unroll
            for (int e = 0; e < 4; e++) alx[e] = __shfl(al, (gq << 2) + e);
#pragma unroll
            for (int f = 0; f < 16; f++)
#pragma unroll
                for (int e = 0; e < 4; e++) oacc[f][e] *= alx[e];
        }
        float rs = 0.f;
#pragma unroll
        for (int n = 0; n < 4; n++)
#pragma unroll
            for (int e = 0; e < 4; e++) {
                float p = __expf(st[n][e] - m_run);
                st[n][e] = p;
                rs += p;
            }
        rs += __shfl_xor(rs, 16);
        rs += __shfl_xor(rs, 32);
        l_run += rs;
        // pack P^T tiles to bf16 (in-register)
        bf16x4 pa0, pa1, pa2, pa3;
#pragma unroll
        for (int e = 0; e < 4; e++) {
            pa0[e] = (bf16)st[0][e];
            pa1[e] = (bf16)st[1][e];
            pa2[e] = (bf16)st[2][e];
            pa3[e] = (bf16)st[3][e];
        }
        bf16x8 af0, af1;
#pragma unroll
        for (int e = 0; e < 4; e++) {
            af0[e] = pa0[e]; af0[e + 4] = pa1[e];
            af1[e] = pa2[e]; af1[e + 4] = pa3[e];
        }
        __builtin_amdgcn_s_setprio(1);
#pragma unroll
        for (int n2 = 0; n2 < 16; n2++) {
            const int rowoff = (n2 * 16 + lr) << 6;
            bf16x4 v00 = *(const bf16x4*)&Vc[rowoff + vco[0]];
            bf16x4 v01 = *(const bf16x4*)&Vc[rowoff + vco[1]];
            bf16x4 v10 = *(const bf16x4*)&Vc[rowoff + vco[2]];
            bf16x4 v11 = *(const bf16x4*)&Vc[rowoff + vco[3]];
            bf16x8 vb0, vb1;
#pragma unroll
            for (int e = 0; e < 4; e++) {
                vb0[e] = v00[e]; vb0[e + 4] = v01[e];
                vb1[e] = v10[e]; vb1[e + 4] = v11[e];
            }
            oacc[n2] = __builtin_amdgcn_mfma_f32_16x16x32_bf16(af0, vb0, oacc[n2], 0, 0, 0);
            oacc[n2] = __builtin_amdgcn_mfma_f32_16x16x32_bf16(af1, vb1, oacc[n2], 0, 0, 0);
        }
        __builtin_amdgcn_s_setprio(0);
        __syncthreads();
        buf ^= 1;
    }
    // final divide: fetch l_run for q = 4*gq+e
    float ldiv[4];
#pragma unroll
    for (int e = 0; e < 4; e++) ldiv[e] = 1.f / __shfl(l_run, (gq << 2) + e);
#pragma unroll
    for (int n2 = 0; n2 < 16; n2++) {
#pragma unroll
        for (int e = 0; e < 4; e++) {
            long row = ((long)c << 10) + q0 + wid * 16 + (gq << 2) + e;
            long col = ((long)h << 8) + n2 * 16 + lr;
            ao[row * 1024 + col] = (bf16)(oacc[n2][e] * ldiv[e]);
        }
    }
}

// ---------------- t = LN(o + mixed) (bf16 in, bf16 out) ----------------
__global__ __launch_bounds__(256) void k_outln(const bf16* __restrict__ o,
                                               const bf16* __restrict__ mixed,
                                               const float* __restrict__ g,
                                               const float* __restrict__ b,
                                               bf16* __restrict__ t) {
    long row = blockIdx.x;
    int tid = threadIdx.x;
    int wid = tid >> 6, lane = tid & 63;
    __shared__ float red1[4], red2[4];
    float x[4];
    const bf16* orow = o + row * 1024;
    const bf16* mrow = mixed + row * 1024;
    bf16x4 ov = *(const bf16x4*)&orow[tid * 4];
    bf16x4 mv = *(const bf16x4*)&mrow[tid * 4];
#pragma unroll
    for (int i = 0; i < 4; i++) x[i] = (float)ov[i] + (float)mv[i];
    float s1 = x[0] + x[1] + x[2] + x[3];
    float s2 = x[0] * x[0] + x[1] * x[1] + x[2] * x[2] + x[3] * x[3];
#pragma unroll
    for (int xm = 1; xm < 64; xm <<= 1) {
        s1 += __shfl_xor(s1, xm);
        s2 += __shfl_xor(s2, xm);
    }
    if (lane == 0) { red1[wid] = s1; red2[wid] = s2; }
    __syncthreads();
    s1 = red1[0] + red1[1] + red1[2] + red1[3];
    s2 = red2[0] + red2[1] + red2[2] + red2[3];
    float mean = s1 * (1.f / 1024.f);
    float var = s2 * (1.f / 1024.f) - mean * mean;
    float inv = rsqrtf(var + 1e-5f);
#pragma unroll
    for (int i = 0; i < 4; i++) {
        int j = tid * 4 + i;
        t[row * 1024 + j] = (bf16)((x[i] - mean) * inv * g[j] + b[j]);
    }
}

extern "C" void kernel_launch(void* const* d_in, const int* in_sizes, int n_in,
                              void* d_out, int out_size, void* d_ws, size_t ws_size,
                              hipStream_t stream) {
    const float* x   = (const float*)d_in[0];
    const float* mw  = (const float*)d_in[1];
    const float* sc  = (const float*)d_in[2];
    const float* w1  = (const float*)d_in[3];
    const float* b1  = (const float*)d_in[4];
    const float* lng1 = (const float*)d_in[5];
    const float* lnb1 = (const float*)d_in[6];
    const float* w2  = (const float*)d_in[7];
    const float* b2  = (const float*)d_in[8];
    const float* wq  = (const float*)d_in[9];
    const float* wk  = (const float*)d_in[10];
    const float* wv  = (const float*)d_in[11];
    const float* wo  = (const float*)d_in[12];
    const float* lng2 = (const float*)d_in[13];
    const float* lnb2 = (const float*)d_in[14];
    const float* ow  = (const float*)d_in[15];
    const float* ob  = (const float*)d_in[16];

    char* p = (char*)d_ws;
    auto take = [&](size_t bytes) {
        char* r = p;
        p += (bytes + 255) & ~(size_t)255;
        return r;
    };
    const size_t M = 16384;
    float* kern   = (float*)take(8 * 1024 * sizeof(float));
    float* coeffs = (float*)take(M * 8 * sizeof(float));
    bf16* g       = (bf16*)take(M * 512 * 2);
    bf16* mixed   = (bf16*)take(M * 1024 * 2);
    bf16* qb      = (bf16*)take(M * 1024 * 2 * 2);  // q then k; q region reused as bf16 o later
    bf16* kb2     = qb + M * 1024;
    bf16* obf     = qb;
    bf16* vtb     = (bf16*)take(M * 1024 * 2);      // v transposed per (chunk,head); reused as t later
    bf16* tb      = vtb;
    bf16* aob     = (bf16*)take(M * 1024 * 2);
    bf16* w2t     = (bf16*)take((size_t)1024 * 512 * 2);
    bf16* wqt     = (bf16*)take((size_t)1024 * 1024 * 2);
    bf16* wkt     = (bf16*)take((size_t)1024 * 1024 * 2);
    bf16* wvt     = (bf16*)take((size_t)1024 * 1024 * 2);
    bf16* wot     = (bf16*)take((size_t)1024 * 1024 * 2);
    bf16* owt     = (bf16*)take((size_t)256 * 1024 * 2);

    k_wavelet<<<8, 256, 0, stream>>>(mw, sc, kern);
    k_coeffs<<<4096, 256, 0, stream>>>(x, kern, coeffs);
    k_mix1<<<16384, 256, 0, stream>>>(coeffs, w1, b1, lng1, lnb1, g);

    // all 6 weight transposes in one launch (4980736 elements / 256)
    k_wtrans_all<<<19456, 256, 0, stream>>>(w2, wq, wk, wv, wo, ow,
                                            w2t, wqt, wkt, wvt, wot, owt);

    // mixed = gelu(hid) @ w2 + b2
    k_gemm8p<EPI_BF16_BIAS><<<dim3(4, 64), 512, 0, stream>>>(
        g, w2t, b2, mixed, 512, 512, 512, 1024, 1.f);
    // q (scaled by hd^-0.5), k, v(transposed layout)
    k_gemm8p<EPI_BF16><<<dim3(4, 64), 512, 0, stream>>>(
        mixed, wqt, nullptr, qb, 1024, 1024, 1024, 1024, 0.0625f);
    k_gemm8p<EPI_BF16><<<dim3(4, 64), 512, 0, stream>>>(
        mixed, wkt, nullptr, kb2, 1024, 1024, 1024, 1024, 1.f);
    k_gemm8p<EPI_VT><<<dim3(4, 64), 512, 0, stream>>>(
        mixed, wvt, nullptr, vtb, 1024, 1024, 1024, 1024, 1.f);
    // attention (8 waves, 128 q-rows per block, KVBLK=64, swapped QK^T)
    k_attn<<<dim3(16, 4, 8), 512, 0, stream>>>(qb, kb2, vtb, aob);
    // o = ao @ wo (bf16, overwrites q region)
    k_gemm8p<EPI_BF16><<<dim3(4, 64), 512, 0, stream>>>(
        aob, wot, nullptr, obf, 1024, 1024, 1024, 1024, 1.f);
    // t = LN(o + mixed) (overwrites vt region)
    k_outln<<<16384, 256, 0, stream>>>(obf, mixed, lng2, lnb2, tb);
    // y = t @ out_w + out_b (N=256 -> 128^2 kernel, grid 256 blocks)
    k_gemm<EPI_F32_BIAS><<<dim3(2, 128), 256, 0, stream>>>(
        tb, owt, ob, d_out, 16384, 256, 1024, 1024, 1024, 256, 1.f);
}

// Round 14
// 408.297 us; speedup vs baseline: 1.0304x; 1.0304x over previous
//
#include <hip/hip_runtime.h>
#include <hip/hip_bf16.h>

typedef __bf16 bf16;
typedef __bf16 bf16x4 __attribute__((ext_vector_type(4)));
typedef __bf16 bf16x8 __attribute__((ext_vector_type(8)));
typedef float f32x4 __attribute__((ext_vector_type(4)));
typedef unsigned short ushort8_t __attribute__((ext_vector_type(8)));
typedef unsigned int u32x2 __attribute__((ext_vector_type(2)));

#define GLOAD_LDS16(g, l)                                                      \
    __builtin_amdgcn_global_load_lds(                                          \
        (const __attribute__((address_space(1))) void*)(g),                    \
        (__attribute__((address_space(3))) void*)(l), 16, 0, 0)

#define LDS_ADDR(p) ((unsigned)(uintptr_t)(__attribute__((address_space(3))) void*)(p))

// pinned raw barrier: sched_barrier(0) fences IR motion across it (rule #18/m152)
#define SBAR()                                                                 \
    do {                                                                       \
        __builtin_amdgcn_sched_barrier(0);                                     \
        __builtin_amdgcn_s_barrier();                                          \
        __builtin_amdgcn_sched_barrier(0);                                     \
    } while (0)

// Problem constants
// B=4, S=4096, H=1024, G=256, W=8, CHUNK=1024, NUM_HEADS=4, hd=256
// M = B*S = 16384 rows, NC = 16 chunks

// ---------------- wavelet kernel normalization ----------------
__global__ __launch_bounds__(256) void k_wavelet(const float* __restrict__ mw,
                                                 const float* __restrict__ sc,
                                                 float* __restrict__ kern) {
    int w = blockIdx.x;
    int tid = threadIdx.x;
    float s = 0.f;
    for (int h = tid; h < 1024; h += 256) { float v = mw[w * 1024 + h]; s += v * v; }
#pragma unroll
    for (int xm = 1; xm < 64; xm <<= 1) s += __shfl_xor(s, xm);
    __shared__ float red[4];
    if ((tid & 63) == 0) red[tid >> 6] = s;
    __syncthreads();
    float tot = red[0] + red[1] + red[2] + red[3];
    float inv = 1.f / fmaxf(sqrtf(tot), 1e-12f);
    float sg = 1.f / (1.f + __expf(-sc[w]));
    float m = inv * sg;
    for (int h = tid; h < 1024; h += 256) kern[w * 1024 + h] = mw[w * 1024 + h] * m;
}

// ---------------- fused: coeffs (8 wavelet dots) + mix1 (LN+GELU) per row ----------------
// grid 4096 x 256 threads; wave wid handles row = blk*4 + wid entirely (no cross-wave dep).
__global__ __launch_bounds__(256) void k_front(const float* __restrict__ x,
                                               const float* __restrict__ kern,
                                               const float* __restrict__ w1,
                                               const float* __restrict__ b1,
                                               const float* __restrict__ lng,
                                               const float* __restrict__ lnb,
                                               bf16* __restrict__ g) {
    __shared__ float kl[8 * 1024];
    int tid = threadIdx.x;
    for (int i = tid; i < 8192; i += 256) kl[i] = kern[i];
    __syncthreads();
    int wid = tid >> 6, lane = tid & 63;
    long row = (long)blockIdx.x * 4 + wid;
    // phase 1: 8 wavelet dots over the 1024-row
    float acc[8] = {0, 0, 0, 0, 0, 0, 0, 0};
    const float* xr = x + row * 1024;
    for (int i = 0; i < 16; i++) {
        float xv = xr[lane + i * 64];
#pragma unroll
        for (int w = 0; w < 8; w++) acc[w] += xv * kl[w * 1024 + lane + i * 64];
    }
#pragma unroll
    for (int xm = 1; xm < 64; xm <<= 1) {
#pragma unroll
        for (int w = 0; w < 8; w++) acc[w] += __shfl_xor(acc[w], xm);
    }
    // phase 2: hid[j] = coeffs . w1[:,j] + b1[j]; LN over 512; gelu; j = lane*8+e
    float h[8];
#pragma unroll
    for (int e = 0; e < 8; e++) {
        int j = lane * 8 + e;
        float a = b1[j];
#pragma unroll
        for (int w = 0; w < 8; w++) a += acc[w] * w1[w * 512 + j];
        h[e] = a;
    }
    float s1 = 0.f, s2 = 0.f;
#pragma unroll
    for (int e = 0; e < 8; e++) { s1 += h[e]; s2 += h[e] * h[e]; }
#pragma unroll
    for (int xm = 1; xm < 64; xm <<= 1) {
        s1 += __shfl_xor(s1, xm);
        s2 += __shfl_xor(s2, xm);
    }
    float mean = s1 * (1.f / 512.f);
    float var = s2 * (1.f / 512.f) - mean * mean;
    float inv = rsqrtf(var + 1e-5f);
    bf16x8 out;
#pragma unroll
    for (int e = 0; e < 8; e++) {
        int j = lane * 8 + e;
        float xn = (h[e] - mean) * inv * lng[j] + lnb[j];
        float ge = 0.5f * xn * (1.f + erff(xn * 0.70710678118654752f));
        out[e] = (bf16)ge;
    }
    *(bf16x8*)&g[row * 512 + lane * 8] = out;
}

// ---------------- coalesced weight transpose: 32x32 LDS tiles, all 6 weights, 1 launch ----------
__global__ __launch_bounds__(256) void k_wtrans_t(const float* __restrict__ w2, const float* __restrict__ wq,
                                                  const float* __restrict__ wk, const float* __restrict__ wv,
                                                  const float* __restrict__ wo, const float* __restrict__ ow,
                                                  bf16* __restrict__ w2t, bf16* __restrict__ wqt,
                                                  bf16* __restrict__ wkt, bf16* __restrict__ wvt,
                                                  bf16* __restrict__ wot, bf16* __restrict__ owt) {
    __shared__ float ld[32][33];
    const int t = blockIdx.x;
    const int tid = threadIdx.x;
    const float* src;
    bf16* dst;
    int K, N, lt;
    if (t < 512)       { src = w2; dst = w2t; K = 512;  N = 1024; lt = t; }
    else if (t < 1536) { src = wq; dst = wqt; K = 1024; N = 1024; lt = t - 512; }
    else if (t < 2560) { src = wk; dst = wkt; K = 1024; N = 1024; lt = t - 1536; }
    else if (t < 3584) { src = wv; dst = wvt; K = 1024; N = 1024; lt = t - 2560; }
    else if (t < 4608) { src = wo; dst = wot; K = 1024; N = 1024; lt = t - 3584; }
    else               { src = ow; dst = owt; K = 1024; N = 256;  lt = t - 4608; }
    int kt, nt_;
    if (t < 4608) { kt = lt >> 5; nt_ = lt & 31; }   // tiles_x = 32
    else          { kt = lt >> 3; nt_ = lt & 7; }    // tiles_x = 8 (ow)
    const int k0 = kt << 5, n0 = nt_ << 5;
    const int tx = tid & 31, ty = tid >> 5;          // ty 0..7
#pragma unroll
    for (int m = 0; m < 4; m++) {
        int r = ty + m * 8;
        ld[r][tx] = src[(long)(k0 + r) * N + n0 + tx];
    }
    __syncthreads();
#pragma unroll
    for (int m = 0; m < 4; m++) {
        int r = ty + m * 8;
        dst[(long)(n0 + r) * K + k0 + tx] = (bf16)ld[tx][r];
    }
}

enum { EPI_BF16 = 0, EPI_BF16_BIAS = 1, EPI_F32_BIAS = 2, EPI_VT = 3, EPI_F32 = 4 };

// ---------------- GEMM 256x256, 8 waves, BK=64, 8-PHASE schedule (T1+T2+T3+T4+T5) ----------------
// verified R10/R12: 460->431->414 us path
template <int EPI>
__global__ __launch_bounds__(512, 2) void k_gemm8p(const bf16* __restrict__ A,
                                                   const bf16* __restrict__ Bt,
                                                   const float* __restrict__ bias,
                                                   void* __restrict__ Cout,
                                                   int K, int lda, int ldb, int ldc,
                                                   float scale) {
    __shared__ bf16 As[2 * 2 * 128 * 64];   // [buf][half][128][64] = 64 KB
    __shared__ bf16 Bs[2 * 2 * 128 * 64];   // 64 KB
    const int tid = threadIdx.x;
    const int wid = tid >> 6, lane = tid & 63;
    const int wr = wid >> 2, wc = wid & 3;   // 2x4 wave grid; wave owns 128x64
    // T1: bijective XCD chunk remap (grid = 4 x 64 = 256 blocks, 256 % 8 == 0)
    const int L = blockIdx.y * 4 + blockIdx.x;
    const int logical = ((L & 7) << 5) + (L >> 3);
    const long m0 = (long)(logical >> 2) * 256, n0 = (long)(logical & 3) * 256;
    f32x4 acc[8][4] = {};
    const int lr = lane & 15, gq = lane >> 4;
    const int l7 = lr & 7;

    const int srow = wid * 8 + (lane >> 3);
    const int sg = (lane & 7) ^ (lane >> 3);
    const bf16* aS = A + (m0 + srow) * lda + sg * 8;
    const bf16* bS = Bt + (n0 + srow) * ldb + sg * 8;

    auto stageA = [&](int t, int h) {
        bf16* d = As + (((t & 1) * 2 + h) * 128) * 64 + wid * 512;
        const long kq = (long)t << 6;
        GLOAD_LDS16(aS + (long)(h * 128) * lda + kq, d);
        GLOAD_LDS16(aS + (long)(h * 128 + 64) * lda + kq, d + 4096);
    };
    auto stageB = [&](int t, int h) {
        bf16* d = Bs + (((t & 1) * 2 + h) * 128) * 64 + wid * 512;
        const long kq = (long)t << 6;
        GLOAD_LDS16(bS + (long)(h * 128) * ldb + kq, d);
        GLOAD_LDS16(bS + (long)(h * 128 + 64) * ldb + kq, d + 4096);
    };

    bf16x8 bfr[4][2];
    auto ldB = [&](int b) {
#pragma unroll
        for (int j = 0; j < 4; j++)
#pragma unroll
            for (int kk = 0; kk < 2; kk++)
                bfr[j][kk] = *(const bf16x8*)&Bs[((b * 2 + (wc >> 1)) * 128 +
                                                 (wc & 1) * 64 + j * 16 + lr) * 64 +
                                                (((kk * 4 + gq) ^ l7) << 3)];
    };

    const int nt = K >> 6;        // K-tiles
    const int niter = nt >> 1;

    // prologue: tile0 (A,B) + B(1); vmcnt(4) leaves B(1) in flight
    stageA(0, 0); stageA(0, 1); stageB(0, 0); stageB(0, 1);
    stageB(1, 0); stageB(1, 1);
    asm volatile("s_waitcnt vmcnt(4)" ::: "memory");
    SBAR();

    for (int jit = 0; jit < niter - 1; ++jit) {
        const int T = jit << 1;
#pragma unroll
        for (int tp = 0; tp < 2; ++tp) {
#pragma unroll
            for (int q = 0; q < 4; ++q) {
                bf16x8 af[2][2];
                if (q == 0) ldB(tp);
#pragma unroll
                for (int ii = 0; ii < 2; ii++)
#pragma unroll
                    for (int kk = 0; kk < 2; kk++)
                        af[ii][kk] = *(const bf16x8*)&As[((tp * 2 + wr) * 128 +
                                                         (q * 2 + ii) * 16 + lr) * 64 +
                                                        (((kk * 4 + gq) ^ l7) << 3)];
                if (tp == 0) {
                    if (q == 0) stageA(T + 1, 0);
                    else if (q == 1) stageA(T + 1, 1);
                    else if (q == 2) stageB(T + 2, 0);
                    else stageB(T + 2, 1);
                } else {
                    if (q == 0) stageA(T + 2, 0);
                    else if (q == 1) stageA(T + 2, 1);
                    else if (q == 2) stageB(T + 3, 0);
                    else stageB(T + 3, 1);
                }
                if (q == 3) asm volatile("s_waitcnt vmcnt(4)" ::: "memory");
                SBAR();
                asm volatile("s_waitcnt lgkmcnt(0)" ::: "memory");
                __builtin_amdgcn_s_setprio(1);
#pragma unroll
                for (int ii = 0; ii < 2; ii++)
#pragma unroll
                    for (int j = 0; j < 4; j++) {
                        acc[q * 2 + ii][j] = __builtin_amdgcn_mfma_f32_16x16x32_bf16(
                            af[ii][0], bfr[j][0], acc[q * 2 + ii][j], 0, 0, 0);
                        acc[q * 2 + ii][j] = __builtin_amdgcn_mfma_f32_16x16x32_bf16(
                            af[ii][1], bfr[j][1], acc[q * 2 + ii][j], 0, 0, 0);
                    }
                __builtin_amdgcn_s_setprio(0);
                SBAR();
            }
        }
    }
    // final iteration (T = nt-2): stage only A(T+1); vmcnt(0) at phase 4
    {
        const int T = nt - 2;
#pragma unroll
        for (int tp = 0; tp < 2; ++tp) {
#pragma unroll
            for (int q = 0; q < 4; ++q) {
                bf16x8 af[2][2];
                if (q == 0) ldB(tp);
#pragma unroll
                for (int ii = 0; ii < 2; ii++)
#pragma unroll
                    for (int kk = 0; kk < 2; kk++)
                        af[ii][kk] = *(const bf16x8*)&As[((tp * 2 + wr) * 128 +
                                                         (q * 2 + ii) * 16 + lr) * 64 +
                                                        (((kk * 4 + gq) ^ l7) << 3)];
                if (tp == 0 && q == 0) stageA(T + 1, 0);
                if (tp == 0 && q == 1) stageA(T + 1, 1);
                if (tp == 0 && q == 3) asm volatile("s_waitcnt vmcnt(0)" ::: "memory");
                SBAR();
                asm volatile("s_waitcnt lgkmcnt(0)" ::: "memory");
                __builtin_amdgcn_s_setprio(1);
#pragma unroll
                for (int ii = 0; ii < 2; ii++)
#pragma unroll
                    for (int j = 0; j < 4; j++) {
                        acc[q * 2 + ii][j] = __builtin_amdgcn_mfma_f32_16x16x32_bf16(
                            af[ii][0], bfr[j][0], acc[q * 2 + ii][j], 0, 0, 0);
                        acc[q * 2 + ii][j] = __builtin_amdgcn_mfma_f32_16x16x32_bf16(
                            af[ii][1], bfr[j][1], acc[q * 2 + ii][j], 0, 0, 0);
                    }
                __builtin_amdgcn_s_setprio(0);
                SBAR();
            }
        }
    }

    const int r0 = (lane >> 4) << 2;
#pragma unroll
    for (int i = 0; i < 8; i++) {
#pragma unroll
        for (int j = 0; j < 4; j++) {
#pragma unroll
            for (int e = 0; e < 4; e++) {
                long m = m0 + wr * 128 + i * 16 + r0 + e;
                long n = n0 + wc * 64 + j * 16 + lr;
                float v = acc[i][j][e] * scale;
                if constexpr (EPI == EPI_BF16_BIAS || EPI == EPI_F32_BIAS) v += bias[n];
                if constexpr (EPI == EPI_F32_BIAS || EPI == EPI_F32) {
                    ((float*)Cout)[m * ldc + n] = v;
                } else if constexpr (EPI == EPI_VT) {
                    long c = m >> 10, s = m & 1023, h = n >> 8, d = n & 255;
                    ((bf16*)Cout)[(((c << 2) + h) << 18) + (d << 10) + s] = (bf16)v;
                } else {
                    ((bf16*)Cout)[m * ldc + n] = (bf16)v;
                }
            }
        }
    }
}

// ---------------- GEMM 128x128 (m97 structure) — for the N=256 final GEMM ----------------
template <int EPI>
__global__ __launch_bounds__(256) void k_gemm(const bf16* __restrict__ A,
                                              const bf16* __restrict__ Bt,
                                              const float* __restrict__ bias,
                                              void* __restrict__ Cout,
                                              int M, int N, int K,
                                              int lda, int ldb, int ldc, float scale) {
    __shared__ bf16 As[128 * 32];
    __shared__ bf16 Bs[128 * 32];
    int tid = threadIdx.x;
    int wid = tid >> 6, lane = tid & 63;
    int wr = wid >> 1, wc = wid & 1;
    // T1 XCD remap (grid 2 x 128 = 256 blocks)
    const int L = blockIdx.y * 2 + blockIdx.x;
    const int logical = ((L & 7) << 5) + (L >> 3);
    long m0 = (long)(logical >> 1) * 128, n0 = (long)(logical & 1) * 128;
    f32x4 acc[4][4] = {};
    const int lr = lane & 15, ko = (lane >> 4) << 3;

    const int srow = wid * 32 + (lane >> 2);
    const int scol = (lane & 3) << 3;
    const bf16* a0 = A + (m0 + srow) * lda + scol;
    const bf16* a1 = A + (m0 + srow + 16) * lda + scol;
    const bf16* b0 = Bt + (n0 + srow) * ldb + scol;
    const bf16* b1 = Bt + (n0 + srow + 16) * ldb + scol;
    bf16* la0 = As + wid * 1024;
    bf16* la1 = As + wid * 1024 + 512;
    bf16* lb0 = Bs + wid * 1024;
    bf16* lb1 = Bs + wid * 1024 + 512;

    for (int k0 = 0; k0 < K; k0 += 32) {
        GLOAD_LDS16(a0 + k0, la0);
        GLOAD_LDS16(a1 + k0, la1);
        GLOAD_LDS16(b0 + k0, lb0);
        GLOAD_LDS16(b1 + k0, lb1);
        __syncthreads();
        bf16x8 af[4], bfr[4];
#pragma unroll
        for (int i = 0; i < 4; i++)
            af[i] = *(const bf16x8*)&As[(wr * 64 + i * 16 + lr) * 32 + ko];
#pragma unroll
        for (int i = 0; i < 4; i++)
            bfr[i] = *(const bf16x8*)&Bs[(wc * 64 + i * 16 + lr) * 32 + ko];
#pragma unroll
        for (int i = 0; i < 4; i++) {
#pragma unroll
            for (int j = 0; j < 4; j++)
                acc[i][j] = __builtin_amdgcn_mfma_f32_16x16x32_bf16(af[i], bfr[j], acc[i][j], 0, 0, 0);
        }
        __syncthreads();
    }
    const int r0 = (lane >> 4) << 2;
#pragma unroll
    for (int i = 0; i < 4; i++) {
#pragma unroll
        for (int j = 0; j < 4; j++) {
#pragma unroll
            for (int e = 0; e < 4; e++) {
                long m = m0 + wr * 64 + i * 16 + r0 + e;
                long n = n0 + wc * 64 + j * 16 + lr;
                float v = acc[i][j][e] * scale;
                if constexpr (EPI == EPI_BF16_BIAS || EPI == EPI_F32_BIAS) v += bias[n];
                if constexpr (EPI == EPI_F32_BIAS || EPI == EPI_F32) {
                    ((float*)Cout)[m * ldc + n] = v;
                } else {
                    ((bf16*)Cout)[m * ldc + n] = (bf16)v;
                }
            }
        }
    }
}

// ---------------- flash attention: 8 waves, 128 q-rows/block, KVBLK=64 (R12 proven) ----------------
__global__ __launch_bounds__(512, 2) void k_attn(const bf16* __restrict__ q,
                                                 const bf16* __restrict__ k,
                                                 const bf16* __restrict__ vt,
                                                 bf16* __restrict__ ao) {
    __shared__ __align__(16) bf16 smem[2 * 16384 + 2 * 16384 + 8192];
    bf16* Ks = smem;            // [2][64][256]
    bf16* Vs = smem + 32768;    // [2][256][64]
    bf16* Ps = smem + 65536;    // [8 waves][64][16]  (PT: k-major, q-minor)
    int tid = threadIdx.x;
    int wid = tid >> 6, lane = tid & 63;
    int c = blockIdx.x, h = blockIdx.y, q0 = blockIdx.z * 128;
    const int lr = lane & 15, gq = lane >> 4, ko = gq << 3;
    const int l7 = lr & 7;

    const int krw = wid * 2 + (lane >> 5);                 // 0..15
    const int kg = (lane & 31) ^ (krw & 7);
    const bf16* ksrc = k + ((long)c << 10) * 1024 + h * 256 + kg * 8;
    const int vrw = wid * 8 + ((lane >> 3) & 7);           // 0..63
    const int vg = (lane & 7) ^ ((lane >> 3) & 7);
    const bf16* vsrc = vt + ((long)(c * 4 + h) << 18) + vg * 8;

    long qrow = ((long)c << 10) + q0 + wid * 16 + lr;
    bf16x8 qf[8];
#pragma unroll
    for (int kk = 0; kk < 8; kk++)
        qf[kk] = *(const bf16x8*)&q[qrow * 1024 + h * 256 + kk * 32 + ko];

    f32x4 oacc[16] = {};
    float m_run[4] = {-1e30f, -1e30f, -1e30f, -1e30f};
    float l_run[4] = {0.f, 0.f, 0.f, 0.f};

    bf16* PT = Ps + (wid << 10);
    const unsigned pva = LDS_ADDR(&PT[(gq << 7) + lr]);

    // prologue: stage kb=0 into buf 0
#pragma unroll
    for (int i = 0; i < 4; i++) {
        GLOAD_LDS16(ksrc + (long)(i * 16 + krw) * 1024, Ks + i * 4096 + wid * 512);
        GLOAD_LDS16(vsrc + (long)(i * 64 + vrw) * 1024, Vs + i * 4096 + wid * 512);
    }
    __syncthreads();
    int buf = 0;
    for (int t = 0; t < 16; t++) {
        if (t < 15) {
            const int kb = (t + 1) << 6;
            const int ob = (buf ^ 1) << 14;
#pragma unroll
            for (int i = 0; i < 4; i++) {
                GLOAD_LDS16(ksrc + (long)(kb + i * 16 + krw) * 1024, Ks + ob + i * 4096 + wid * 512);
                GLOAD_LDS16(vsrc + (long)(i * 64 + vrw) * 1024 + kb, Vs + ob + i * 4096 + wid * 512);
            }
        }
        const bf16* Kc = Ks + (buf << 14);
        const bf16* Vc = Vs + (buf << 14);
        f32x4 s[4] = {};
        __builtin_amdgcn_s_setprio(1);
#pragma unroll
        for (int kk = 0; kk < 8; kk++) {
#pragma unroll
            for (int n = 0; n < 4; n++)
                s[n] = __builtin_amdgcn_mfma_f32_16x16x32_bf16(
                    qf[kk],
                    *(const bf16x8*)&Kc[((n * 16 + lr) << 8) + ((((kk << 2) + gq) ^ l7) << 3)],
                    s[n], 0, 0, 0);
        }
        __builtin_amdgcn_s_setprio(0);
        // row max of this tile
        float mx[4];
#pragma unroll
        for (int e = 0; e < 4; e++)
            mx[e] = fmaxf(fmaxf(s[0][e], s[1][e]), fmaxf(s[2][e], s[3][e]));
#pragma unroll
        for (int xm = 1; xm < 16; xm <<= 1) {
#pragma unroll
            for (int e = 0; e < 4; e++) mx[e] = fmaxf(mx[e], __shfl_xor(mx[e], xm));
        }
        // defer-max: rescale only if some row's max grew by > THR
        bool need = (mx[0] > m_run[0] + 8.f) || (mx[1] > m_run[1] + 8.f) ||
                    (mx[2] > m_run[2] + 8.f) || (mx[3] > m_run[3] + 8.f);
        if (__any(need)) {
#pragma unroll
            for (int e = 0; e < 4; e++) {
                float mn = fmaxf(m_run[e], mx[e]);
                float al = __expf(m_run[e] - mn);
                m_run[e] = mn;
                l_run[e] *= al;
#pragma unroll
                for (int f = 0; f < 16; f++) oacc[f][e] *= al;
            }
        }
        float rs[4] = {0.f, 0.f, 0.f, 0.f};
#pragma unroll
        for (int n = 0; n < 4; n++) {
#pragma unroll
            for (int e = 0; e < 4; e++) {
                float p = __expf(s[n][e] - m_run[e]);
                s[n][e] = p;
                rs[e] += p;
            }
        }
#pragma unroll
        for (int xm = 1; xm < 16; xm <<= 1) {
#pragma unroll
            for (int e = 0; e < 4; e++) rs[e] += __shfl_xor(rs[e], xm);
        }
#pragma unroll
        for (int e = 0; e < 4; e++) l_run[e] += rs[e];
        // P -> PT[k][q]: lane's 4 q-rows contiguous -> one b64 write per n
#pragma unroll
        for (int n = 0; n < 4; n++) {
            bf16x4 pv = {(bf16)s[n][0], (bf16)s[n][1], (bf16)s[n][2], (bf16)s[n][3]};
            *(bf16x4*)&PT[((n * 16 + lr) << 4) + (gq << 2)] = pv;
        }
        asm volatile("s_waitcnt lgkmcnt(0)" ::: "memory");
        // tr-read A-fragments: pf0 = P[q=lr][k=8gq..8gq+7], pf1 = +32 k
        u32x2 t0, t1, t2, t3;
        asm volatile("ds_read_b64_tr_b16 %0, %1" : "=v"(t0) : "v"(pva));
        asm volatile("ds_read_b64_tr_b16 %0, %1 offset:128" : "=v"(t1) : "v"(pva));
        asm volatile("ds_read_b64_tr_b16 %0, %1 offset:1024" : "=v"(t2) : "v"(pva));
        asm volatile("ds_read_b64_tr_b16 %0, %1 offset:1152" : "=v"(t3) : "v"(pva));
        asm volatile("s_waitcnt lgkmcnt(0)" ::: "memory");
        __builtin_amdgcn_sched_barrier(0);
        union { u32x2 u[2]; bf16x8 v; } p0, p1;
        p0.u[0] = t0; p0.u[1] = t1;
        p1.u[0] = t2; p1.u[1] = t3;
        const bf16x8 pf0 = p0.v, pf1 = p1.v;
        __builtin_amdgcn_s_setprio(1);
#pragma unroll
        for (int n2 = 0; n2 < 16; n2++) {
            const int vrow = (n2 * 16 + lr) << 6;
            const int vswz = gq ^ l7;
            oacc[n2] = __builtin_amdgcn_mfma_f32_16x16x32_bf16(
                pf0, *(const bf16x8*)&Vc[vrow + (vswz << 3)], oacc[n2], 0, 0, 0);
            oacc[n2] = __builtin_amdgcn_mfma_f32_16x16x32_bf16(
                pf1, *(const bf16x8*)&Vc[vrow + ((vswz ^ 4) << 3)], oacc[n2], 0, 0, 0);
        }
        __builtin_amdgcn_s_setprio(0);
        __syncthreads();
        buf ^= 1;
    }
#pragma unroll
    for (int n2 = 0; n2 < 16; n2++) {
#pragma unroll
        for (int e = 0; e < 4; e++) {
            long row = ((long)c << 10) + q0 + wid * 16 + (gq << 2) + e;
            long col = ((long)h << 8) + n2 * 16 + lr;
            ao[row * 1024 + col] = (bf16)(oacc[n2][e] / l_run[e]);
        }
    }
}

// ---------------- t = LN(o + mixed) (bf16 in, bf16 out) ----------------
__global__ __launch_bounds__(256) void k_outln(const bf16* __restrict__ o,
                                               const bf16* __restrict__ mixed,
                                               const float* __restrict__ g,
                                               const float* __restrict__ b,
                                               bf16* __restrict__ t) {
    long row = blockIdx.x;
    int tid = threadIdx.x;
    int wid = tid >> 6, lane = tid & 63;
    __shared__ float red1[4], red2[4];
    float x[4];
    const bf16* orow = o + row * 1024;
    const bf16* mrow = mixed + row * 1024;
    bf16x4 ov = *(const bf16x4*)&orow[tid * 4];
    bf16x4 mv = *(const bf16x4*)&mrow[tid * 4];
#pragma unroll
    for (int i = 0; i < 4; i++) x[i] = (float)ov[i] + (float)mv[i];
    float s1 = x[0] + x[1] + x[2] + x[3];
    float s2 = x[0] * x[0] + x[1] * x[1] + x[2] * x[2] + x[3] * x[3];
#pragma unroll
    for (int xm = 1; xm < 64; xm <<= 1) {
        s1 += __shfl_xor(s1, xm);
        s2 += __shfl_xor(s2, xm);
    }
    if (lane == 0) { red1[wid] = s1; red2[wid] = s2; }
    __syncthreads();
    s1 = red1[0] + red1[1] + red1[2] + red1[3];
    s2 = red2[0] + red2[1] + red2[2] + red2[3];
    float mean = s1 * (1.f / 1024.f);
    float var = s2 * (1.f / 1024.f) - mean * mean;
    float inv = rsqrtf(var + 1e-5f);
#pragma unroll
    for (int i = 0; i < 4; i++) {
        int j = tid * 4 + i;
        t[row * 1024 + j] = (bf16)((x[i] - mean) * inv * g[j] + b[j]);
    }
}

extern "C" void kernel_launch(void* const* d_in, const int* in_sizes, int n_in,
                              void* d_out, int out_size, void* d_ws, size_t ws_size,
                              hipStream_t stream) {
    const float* x   = (const float*)d_in[0];
    const float* mw  = (const float*)d_in[1];
    const float* sc  = (const float*)d_in[2];
    const float* w1  = (const float*)d_in[3];
    const float* b1  = (const float*)d_in[4];
    const float* lng1 = (const float*)d_in[5];
    const float* lnb1 = (const float*)d_in[6];
    const float* w2  = (const float*)d_in[7];
    const float* b2  = (const float*)d_in[8];
    const float* wq  = (const float*)d_in[9];
    const float* wk  = (const float*)d_in[10];
    const float* wv  = (const float*)d_in[11];
    const float* wo  = (const float*)d_in[12];
    const float* lng2 = (const float*)d_in[13];
    const float* lnb2 = (const float*)d_in[14];
    const float* ow  = (const float*)d_in[15];
    const float* ob  = (const float*)d_in[16];

    char* p = (char*)d_ws;
    auto take = [&](size_t bytes) {
        char* r = p;
        p += (bytes + 255) & ~(size_t)255;
        return r;
    };
    const size_t M = 16384;
    float* kern   = (float*)take(8 * 1024 * sizeof(float));
    bf16* g       = (bf16*)take(M * 512 * 2);
    bf16* mixed   = (bf16*)take(M * 1024 * 2);
    bf16* qb      = (bf16*)take(M * 1024 * 2 * 2);  // q then k; q region reused as bf16 o later
    bf16* kb2     = qb + M * 1024;
    bf16* obf     = qb;
    bf16* vtb     = (bf16*)take(M * 1024 * 2);      // v transposed per (chunk,head); reused as t later
    bf16* tb      = vtb;
    bf16* aob     = (bf16*)take(M * 1024 * 2);
    bf16* w2t     = (bf16*)take((size_t)1024 * 512 * 2);
    bf16* wqt     = (bf16*)take((size_t)1024 * 1024 * 2);
    bf16* wkt     = (bf16*)take((size_t)1024 * 1024 * 2);
    bf16* wvt     = (bf16*)take((size_t)1024 * 1024 * 2);
    bf16* wot     = (bf16*)take((size_t)1024 * 1024 * 2);
    bf16* owt     = (bf16*)take((size_t)256 * 1024 * 2);

    k_wavelet<<<8, 256, 0, stream>>>(mw, sc, kern);
    // fused coeffs + mix1 (one wave per row)
    k_front<<<4096, 256, 0, stream>>>(x, kern, w1, b1, lng1, lnb1, g);

    // coalesced 32x32 LDS-tile transpose, all 6 weights (4864 tiles)
    k_wtrans_t<<<4864, 256, 0, stream>>>(w2, wq, wk, wv, wo, ow,
                                         w2t, wqt, wkt, wvt, wot, owt);

    // mixed = gelu(hid) @ w2 + b2
    k_gemm8p<EPI_BF16_BIAS><<<dim3(4, 64), 512, 0, stream>>>(
        g, w2t, b2, mixed, 512, 512, 512, 1024, 1.f);
    // q (scaled by hd^-0.5), k, v(transposed layout)
    k_gemm8p<EPI_BF16><<<dim3(4, 64), 512, 0, stream>>>(
        mixed, wqt, nullptr, qb, 1024, 1024, 1024, 1024, 0.0625f);
    k_gemm8p<EPI_BF16><<<dim3(4, 64), 512, 0, stream>>>(
        mixed, wkt, nullptr, kb2, 1024, 1024, 1024, 1024, 1.f);
    k_gemm8p<EPI_VT><<<dim3(4, 64), 512, 0, stream>>>(
        mixed, wvt, nullptr, vtb, 1024, 1024, 1024, 1024, 1.f);
    // attention (8 waves, 128 q-rows per block, KVBLK=64)
    k_attn<<<dim3(16, 4, 8), 512, 0, stream>>>(qb, kb2, vtb, aob);
    // o = ao @ wo (bf16, overwrites q region)
    k_gemm8p<EPI_BF16><<<dim3(4, 64), 512, 0, stream>>>(
        aob, wot, nullptr, obf, 1024, 1024, 1024, 1024, 1.f);
    // t = LN(o + mixed) (overwrites vt region)
    k_outln<<<16384, 256, 0, stream>>>(obf, mixed, lng2, lnb2, tb);
    // y = t @ out_w + out_b (N=256 -> 128^2 kernel, grid 256 blocks)
    k_gemm<EPI_F32_BIAS><<<dim3(2, 128), 256, 0, stream>>>(
        tb, owt, ob, d_out, 16384, 256, 1024, 1024, 1024, 256, 1.f);
}